// Round 4
// baseline (444.952 us; speedup 1.0000x reference)
//
#include <hip/hip_runtime.h>
#include <stdint.h>

// DP_Attention: B=8, S=4096, D=K=1024, fp32.
// Fused structure (6 dispatches):
//   memset(fq, seed_acc)
//   k_prep : blocks 0-255 fq = q@Wq+bq (split-K atomic); 256-511 wvt = bf16(Wv^T)
//   k_gcb  : blocks 0-2047 g[b]=Wk@fq[b]; 2048-2055 cb[b]=fq[b].bk
//   k_attn : attn = sigmoid((g.k_s+cb)/32)  -> d_out[8192:] and attn_ws
//   k_fv   : 1024-thr block: 64 fv rows x FULL N=1024, 16 waves (64 cols each),
//            acc[4][4]=64 regs/lane -> 4 waves/SIMD resident. BK=128 A-tile
//            (16KB swizzled LDS, reg-prefetched). B (wvt, 2MB L2-resident) read
//            per-fragment from global. Row norm in-block -> coef ->
//            atomicAdd sum_s coef*(fv+bv) into seed_acc.
//   k_final: out = seed_acc + 0.1*noise (threefry, partitioned)

#define Bn 8
#define Sn 4096
#define Dn 1024
#define Kn 1024

typedef unsigned short u16;
typedef __attribute__((ext_vector_type(8))) unsigned short u16x8;
typedef __attribute__((ext_vector_type(8))) __bf16 bf16x8;
typedef __attribute__((ext_vector_type(4))) float f32x4;

__device__ __forceinline__ u16 f2bf(float f) {
  uint32_t x = __float_as_uint(f);
  x += 0x7FFFu + ((x >> 16) & 1u);   // RNE
  return (u16)(x >> 16);
}

// ---------------- JAX threefry2x32 (key=(0,1234)), partitionable ----------------
__device__ __forceinline__ uint32_t rotl32(uint32_t x, int d) {
  return (x << d) | (x >> (32 - d));
}
__device__ void threefry2x32(uint32_t k0, uint32_t k1, uint32_t x0, uint32_t x1,
                             uint32_t* o0, uint32_t* o1) {
  uint32_t ks0 = k0, ks1 = k1, ks2 = k0 ^ k1 ^ 0x1BD11BDAu;
  x0 += ks0; x1 += ks1;
#define TF_R4(a,b,c,d) \
  x0 += x1; x1 = rotl32(x1,a); x1 ^= x0; \
  x0 += x1; x1 = rotl32(x1,b); x1 ^= x0; \
  x0 += x1; x1 = rotl32(x1,c); x1 ^= x0; \
  x0 += x1; x1 = rotl32(x1,d); x1 ^= x0;
  TF_R4(13,15,26,6);  x0 += ks1; x1 += ks2 + 1u;
  TF_R4(17,29,16,24); x0 += ks2; x1 += ks0 + 2u;
  TF_R4(13,15,26,6);  x0 += ks0; x1 += ks1 + 3u;
  TF_R4(17,29,16,24); x0 += ks1; x1 += ks2 + 4u;
  TF_R4(13,15,26,6);  x0 += ks2; x1 += ks0 + 5u;
#undef TF_R4
  *o0 = x0; *o1 = x1;
}

__device__ float erfinv_f(float x) {
  float w = -log1pf(-x * x);
  float p;
  if (w < 5.0f) {
    w -= 2.5f;
    p = 2.81022636e-08f;
    p = fmaf(p, w, 3.43273939e-07f);
    p = fmaf(p, w, -3.5233877e-06f);
    p = fmaf(p, w, -4.39150654e-06f);
    p = fmaf(p, w, 0.00021858087f);
    p = fmaf(p, w, -0.00125372503f);
    p = fmaf(p, w, -0.00417768164f);
    p = fmaf(p, w, 0.246640727f);
    p = fmaf(p, w, 1.50140941f);
  } else {
    w = sqrtf(w) - 3.0f;
    p = -0.000200214257f;
    p = fmaf(p, w, 0.000100950558f);
    p = fmaf(p, w, 0.00134934322f);
    p = fmaf(p, w, -0.00367342844f);
    p = fmaf(p, w, 0.00573950773f);
    p = fmaf(p, w, -0.0076224613f);
    p = fmaf(p, w, 0.00943887047f);
    p = fmaf(p, w, 1.00167406f);
    p = fmaf(p, w, 2.83297682f);
  }
  return p * x;
}

// ---------------- k_prep: fq (blocks 0-255) + Wv transpose (blocks 256-511) -----
__global__ void k_prep(const float* __restrict__ q, const float* __restrict__ wq,
                       const float* __restrict__ bq, float* __restrict__ fq,
                       const float* __restrict__ wv, u16* __restrict__ wvt) {
  __shared__ u16 tile[64][72];
  int tid = threadIdx.x;
  if (blockIdx.x < 256) {
    int blk = blockIdx.x;               // b(8) x jc(4) x dc(8)
    int b = blk >> 5, jc = (blk >> 3) & 3, dc = blk & 7;
    int j = jc * 256 + tid;
    const float* qb = q + b * Dn;
    float acc = 0.f;
    int d0 = dc * 128;
    for (int d = d0; d < d0 + 128; ++d)
      acc = fmaf(qb[d], wq[(size_t)d * Kn + j], acc);
    if (dc == 0) acc += bq[j];
    atomicAdd(&fq[b * Kn + j], acc);
  } else {
    int idx = blockIdx.x - 256;
    int k0 = (idx & 15) * 64, n0 = (idx >> 4) * 64;
    int r = tid >> 2, c0 = (tid & 3) * 16;
#pragma unroll
    for (int i = 0; i < 4; ++i) {
      float4 vv = *reinterpret_cast<const float4*>(wv + (size_t)(k0 + r) * Kn + n0 + c0 + i * 4);
      tile[r][c0 + i * 4 + 0] = f2bf(vv.x);
      tile[r][c0 + i * 4 + 1] = f2bf(vv.y);
      tile[r][c0 + i * 4 + 2] = f2bf(vv.z);
      tile[r][c0 + i * 4 + 3] = f2bf(vv.w);
    }
    __syncthreads();
    int n = tid >> 2, kc = (tid & 3) * 16;
    alignas(16) u16 o[16];
#pragma unroll
    for (int i = 0; i < 16; ++i) o[i] = tile[kc + i][n];
    *reinterpret_cast<u16x8*>(wvt + (size_t)(n0 + n) * Kn + k0 + kc)     = *reinterpret_cast<u16x8*>(&o[0]);
    *reinterpret_cast<u16x8*>(wvt + (size_t)(n0 + n) * Kn + k0 + kc + 8) = *reinterpret_cast<u16x8*>(&o[8]);
  }
}

// ---------------- k_gcb: g (blocks 0-2047) + cb (blocks 2048-2055) ----------------
__global__ void k_gcb(const float* __restrict__ wk, const float* __restrict__ fq,
                      const float* __restrict__ bk, float* __restrict__ g,
                      float* __restrict__ cb) {
  int tid = threadIdx.x;
  if (blockIdx.x < 2048) {
    int wid = (blockIdx.x * 256 + tid) >> 6;   // 8192 waves
    int lane = tid & 63;
    int b = wid >> 10, d = wid & 1023;
    const float* row = wk + (size_t)d * Kn;
    const float* f = fq + b * Kn;
    float acc = 0.f;
    for (int j = lane; j < Kn; j += 64) acc = fmaf(row[j], f[j], acc);
    for (int m = 32; m; m >>= 1) acc += __shfl_xor(acc, m, 64);
    if (lane == 0) g[b * Dn + d] = acc;
  } else if (tid < 64) {
    int b = blockIdx.x - 2048;
    float acc = 0.f;
    for (int j = tid; j < Kn; j += 64) acc = fmaf(fq[b * Kn + j], bk[j], acc);
    for (int m = 32; m; m >>= 1) acc += __shfl_xor(acc, m, 64);
    if (tid == 0) cb[b] = acc;
  }
}

// ---------------- attn = sigmoid((g.k_s + cb)/32), dual store ----------------
__global__ void k_attn(const float* __restrict__ kmat, const float* __restrict__ g,
                       const float* __restrict__ cb, float* __restrict__ out_attn,
                       float* __restrict__ attn_ws) {
  int row = blockIdx.x * 4 + (threadIdx.x >> 6);  // 32768
  int lane = threadIdx.x & 63;
  int b = row >> 12;
  const float4* kr = reinterpret_cast<const float4*>(kmat + (size_t)row * Dn);
  const float4* gr = reinterpret_cast<const float4*>(g + b * Dn);
  float acc = 0.f;
#pragma unroll
  for (int i = 0; i < 4; ++i) {
    float4 kv = kr[lane + 64 * i];
    float4 gv = gr[lane + 64 * i];
    acc = fmaf(kv.x, gv.x, acc); acc = fmaf(kv.y, gv.y, acc);
    acc = fmaf(kv.z, gv.z, acc); acc = fmaf(kv.w, gv.w, acc);
  }
  for (int m = 32; m; m >>= 1) acc += __shfl_xor(acc, m, 64);
  if (lane == 0) {
    float logit = (acc + cb[b]) * 0.03125f;
    float s = 1.f / (1.f + expf(-logit));
    out_attn[row] = s;
    attn_ws[row] = s;
  }
}

// ---------------- k_fv: fused fv GEMM + norm/clip + weighted seed reduce ---------
// 1024 threads = 16 waves; wave w owns cols [w*64,(w+1)*64) (4 col-tiles of 16).
// Block covers 64 rows (one b) x full N=1024. acc[4][4] = 64 regs/lane ->
// launch_bounds(1024) caps total at 128 -> 4 waves/SIMD resident.
// A-tile: As[64][128] bf16 (16KB), XOR-swizzled (row r = 16 chunks of 16B;
// chunk c stored at pos c^(r&15)); each thread stages exactly one chunk,
// fp32 source reg-prefetched one K-step ahead. B read directly from wvt
// (2MB, L2-resident): 16B fragment per (ct,j).
__global__ __launch_bounds__(1024)
void k_fv(const float* __restrict__ v, const u16* __restrict__ wvt,
          const float* __restrict__ bv, const float* __restrict__ attn,
          float* __restrict__ seed_acc) {
  __shared__ u16 As[64 * 128];     // 16 KiB
  __shared__ float nrm[64];
  __shared__ float coef[64];

  int r0 = blockIdx.x * 64;
  int b  = r0 >> 12;
  int s0 = r0 & (Sn - 1);

  int tid = threadIdx.x;
  int wave = tid >> 6, lane = tid & 63;
  int m = lane & 15, qq = lane >> 4;

  if (tid < 64) nrm[tid] = 0.f;

  f32x4 acc[4][4];
#pragma unroll
  for (int i = 0; i < 4; ++i)
#pragma unroll
    for (int j = 0; j < 4; ++j) acc[i][j] = (f32x4){0.f, 0.f, 0.f, 0.f};

  // A staging: thread -> row tid>>4 (0..63), chunk tid&15 (0..15)
  int arow = tid >> 4, achunk = tid & 15;
  const float* gA0 = v + ((size_t)(b * Sn + s0) + arow) * Dn + achunk * 8;
  int apos = (achunk ^ (arow & 15)) * 8;   // u16 offset within row (swizzled)

  // B base per lane: rows wave*64 + ct*16 + m of wvt
  const u16* gB = wvt + (size_t)(wave * 64 + m) * Kn;

  // prefetch first A chunk (8 floats)
  float4 pa0 = reinterpret_cast<const float4*>(gA0)[0];
  float4 pa1 = reinterpret_cast<const float4*>(gA0)[1];

  for (int k0 = 0; k0 < 1024; k0 += 128) {
    __syncthreads();
    {
      u16x8 o = { f2bf(pa0.x), f2bf(pa0.y), f2bf(pa0.z), f2bf(pa0.w),
                  f2bf(pa1.x), f2bf(pa1.y), f2bf(pa1.z), f2bf(pa1.w) };
      *reinterpret_cast<u16x8*>(&As[arow * 128 + apos]) = o;
    }
    if (k0 < 896) {   // issue next A load; overlaps with MFMA below
      const float4* pa = reinterpret_cast<const float4*>(gA0 + k0 + 128);
      pa0 = pa[0]; pa1 = pa[1];
    }
    __syncthreads();

#pragma unroll
    for (int j = 0; j < 4; ++j) {
      int c = j * 4 + qq;               // chunk 0..15 (K-slice c*8)
      bf16x8 a[4];
#pragma unroll
      for (int rt = 0; rt < 4; ++rt) {
        int r = rt * 16 + m;
        u16x8 raw = *reinterpret_cast<const u16x8*>(&As[r * 128 + ((c ^ (r & 15)) * 8)]);
        a[rt] = __builtin_bit_cast(bf16x8, raw);
      }
#pragma unroll
      for (int ct = 0; ct < 4; ++ct) {
        u16x8 raw = *reinterpret_cast<const u16x8*>(gB + (size_t)ct * 16 * Kn + k0 + c * 8);
        bf16x8 bb = __builtin_bit_cast(bf16x8, raw);
#pragma unroll
        for (int rt = 0; rt < 4; ++rt)
          acc[rt][ct] = __builtin_amdgcn_mfma_f32_16x16x32_bf16(a[rt], bb, acc[rt][ct], 0, 0, 0);
      }
    }
  }

  // bias per owned col (C/D layout: col = lane&15, row = qq*4+reg)
  float bvv[4];
#pragma unroll
  for (int ct = 0; ct < 4; ++ct) bvv[ct] = bv[wave * 64 + ct * 16 + m];

  // row sum-of-squares: per (rt,reg) sum this lane's 4 cols, reduce over m
#pragma unroll
  for (int rt = 0; rt < 4; ++rt) {
#pragma unroll
    for (int reg = 0; reg < 4; ++reg) {
      float ss = 0.f;
#pragma unroll
      for (int ct = 0; ct < 4; ++ct) {
        float f = acc[rt][ct][reg] + bvv[ct];
        ss = fmaf(f, f, ss);
      }
      ss += __shfl_xor(ss, 1, 64);
      ss += __shfl_xor(ss, 2, 64);
      ss += __shfl_xor(ss, 4, 64);
      ss += __shfl_xor(ss, 8, 64);
      if (m == 0) atomicAdd(&nrm[rt * 16 + qq * 4 + reg], ss);
    }
  }
  __syncthreads();
  if (tid < 64)
    coef[tid] = attn[b * Sn + s0 + tid] / fmaxf(1.f, sqrtf(nrm[tid]));
  __syncthreads();

  // weighted reduce over rows: seed[b, col] += sum_rows coef[row]*(fv+bv)
#pragma unroll
  for (int ct = 0; ct < 4; ++ct) {
    float t = 0.f;
#pragma unroll
    for (int rt = 0; rt < 4; ++rt) {
#pragma unroll
      for (int reg = 0; reg < 4; ++reg) {
        float cf = coef[rt * 16 + qq * 4 + reg];
        t = fmaf(cf, acc[rt][ct][reg] + bvv[ct], t);
      }
    }
    t += __shfl_xor(t, 16, 64);
    t += __shfl_xor(t, 32, 64);
    if (qq == 0) atomicAdd(&seed_acc[b * Kn + wave * 64 + ct * 16 + m], t);
  }
}

// ---------------- k_final: out = seed_acc + 0.1*noise ----------------
__global__ void k_final(const float* __restrict__ seed_acc, float* __restrict__ out) {
  int t = blockIdx.x * 256 + threadIdx.x;   // 8192
  uint32_t o0, o1;
  threefry2x32(0u, 1234u, 0u, (uint32_t)t, &o0, &o1);
  uint32_t bits = o0 ^ o1;
  float f = __uint_as_float((bits >> 9) | 0x3F800000u) - 1.0f;
  float lo = __uint_as_float(0xBF7FFFFFu);
  float u = f * (1.0f - lo) + lo;
  u = fmaxf(u, lo);
  out[t] = seed_acc[t] + 1.41421356237f * erfinv_f(u) * 0.1f;
}

extern "C" void kernel_launch(void* const* d_in, const int* in_sizes, int n_in,
                              void* d_out, int out_size, void* d_ws, size_t ws_size,
                              hipStream_t stream) {
  const float* q  = (const float*)d_in[0];
  const float* k  = (const float*)d_in[1];
  const float* v  = (const float*)d_in[2];
  const float* wq = (const float*)d_in[3];
  const float* bq = (const float*)d_in[4];
  const float* wk = (const float*)d_in[5];
  const float* bk = (const float*)d_in[6];
  const float* wv = (const float*)d_in[7];
  const float* bv = (const float*)d_in[8];
  float* out = (float*)d_out;
  float* ws = (float*)d_ws;

  // ws floats: fq[0,8192) seed_acc[8192,16384) g[16384,24576) cb[24576,24584)
  //            attn_ws[24832,57600) ; wvt bytes @ [262144, 262144+2MiB)
  float* fq       = ws;
  float* seed_acc = ws + 8192;
  float* g        = ws + 16384;
  float* cb       = ws + 24576;
  float* attn_ws  = ws + 24832;
  u16* wvt = (u16*)((char*)d_ws + 262144);

  hipMemsetAsync(ws, 0, 16384 * sizeof(float), stream);       // fq + seed_acc
  k_prep <<<512,  256, 0, stream>>>(q, wq, bq, fq, wv, wvt);
  k_gcb  <<<2056, 256, 0, stream>>>(wk, fq, bk, g, cb);
  k_attn <<<8192, 256, 0, stream>>>(k, g, cb, out + 8192, attn_ws);
  k_fv   <<<512, 1024, 0, stream>>>(v, wvt, bv, attn_ws, seed_acc);
  k_final<<<32,   256, 0, stream>>>(seed_acc, out);
}

// Round 5
// 396.022 us; speedup vs baseline: 1.1236x; 1.1236x over previous
//
#include <hip/hip_runtime.h>
#include <stdint.h>

// DP_Attention: B=8, S=4096, D=K=1024, fp32.
// Fused structure (6 dispatches):
//   memset(fq, seed_acc)
//   k_prep : blocks 0-255 fq = q@Wq+bq (split-K atomic); 256-511 wvtp = bf16 Wv
//            packed in MFMA-fragment order (per 16-col tile x 32-k slice: 64
//            lanes' 16B fragments contiguous -> k_fv B loads are lane*16B coalesced)
//   k_gcb  : blocks 0-2047 g[b]=Wk@fq[b]; 2048-2055 cb[b]=fq[b].bk
//   k_attn : attn = sigmoid((g.k_s+cb)/32)  -> d_out[8192:] and attn_ws
//   k_fv   : 1024-thr block: 64 fv rows x FULL N=1024, 16 waves (64 cols each),
//            acc[4][4]=64 regs/lane. BK=128 A-tile (16KB swizzled LDS,
//            reg-prefetched). B from wvtp: 1KB coalesced loads, L2-resident.
//            Row norm in-block -> coef -> atomicAdd sum_s coef*(fv+bv) into seed_acc.
//   k_final: out = seed_acc + 0.1*noise (threefry, partitioned)
// R4 post-mortem: scattered per-lane B gathers (16 rows/instr) saturated the VMEM
// front-end (perf tracked gather count, not occupancy). Packed layout removes them.

#define Bn 8
#define Sn 4096
#define Dn 1024
#define Kn 1024

typedef unsigned short u16;
typedef __attribute__((ext_vector_type(8))) unsigned short u16x8;
typedef __attribute__((ext_vector_type(8))) __bf16 bf16x8;
typedef __attribute__((ext_vector_type(4))) float f32x4;

__device__ __forceinline__ u16 f2bf(float f) {
  uint32_t x = __float_as_uint(f);
  x += 0x7FFFu + ((x >> 16) & 1u);   // RNE
  return (u16)(x >> 16);
}

// ---------------- JAX threefry2x32 (key=(0,1234)), partitionable ----------------
__device__ __forceinline__ uint32_t rotl32(uint32_t x, int d) {
  return (x << d) | (x >> (32 - d));
}
__device__ void threefry2x32(uint32_t k0, uint32_t k1, uint32_t x0, uint32_t x1,
                             uint32_t* o0, uint32_t* o1) {
  uint32_t ks0 = k0, ks1 = k1, ks2 = k0 ^ k1 ^ 0x1BD11BDAu;
  x0 += ks0; x1 += ks1;
#define TF_R4(a,b,c,d) \
  x0 += x1; x1 = rotl32(x1,a); x1 ^= x0; \
  x0 += x1; x1 = rotl32(x1,b); x1 ^= x0; \
  x0 += x1; x1 = rotl32(x1,c); x1 ^= x0; \
  x0 += x1; x1 = rotl32(x1,d); x1 ^= x0;
  TF_R4(13,15,26,6);  x0 += ks1; x1 += ks2 + 1u;
  TF_R4(17,29,16,24); x0 += ks2; x1 += ks0 + 2u;
  TF_R4(13,15,26,6);  x0 += ks0; x1 += ks1 + 3u;
  TF_R4(17,29,16,24); x0 += ks1; x1 += ks2 + 4u;
  TF_R4(13,15,26,6);  x0 += ks2; x1 += ks0 + 5u;
#undef TF_R4
  *o0 = x0; *o1 = x1;
}

__device__ float erfinv_f(float x) {
  float w = -log1pf(-x * x);
  float p;
  if (w < 5.0f) {
    w -= 2.5f;
    p = 2.81022636e-08f;
    p = fmaf(p, w, 3.43273939e-07f);
    p = fmaf(p, w, -3.5233877e-06f);
    p = fmaf(p, w, -4.39150654e-06f);
    p = fmaf(p, w, 0.00021858087f);
    p = fmaf(p, w, -0.00125372503f);
    p = fmaf(p, w, -0.00417768164f);
    p = fmaf(p, w, 0.246640727f);
    p = fmaf(p, w, 1.50140941f);
  } else {
    w = sqrtf(w) - 3.0f;
    p = -0.000200214257f;
    p = fmaf(p, w, 0.000100950558f);
    p = fmaf(p, w, 0.00134934322f);
    p = fmaf(p, w, -0.00367342844f);
    p = fmaf(p, w, 0.00573950773f);
    p = fmaf(p, w, -0.0076224613f);
    p = fmaf(p, w, 0.00943887047f);
    p = fmaf(p, w, 1.00167406f);
    p = fmaf(p, w, 2.83297682f);
  }
  return p * x;
}

// ---------------- k_prep: fq (blocks 0-255) + Wv pack (blocks 256-511) ----------
// Packed layout (u16 units): for global col n, k:
//   off = ((n>>4)*32 + (k>>5))*512 + (((k>>3)&3)*16 + (n&15))*8 + (k&7)
// i.e. per (16-col tile, 32-k slice): 64 lanes x 8 u16, lane = ((k>>3)&3)*16+(n&15).
__global__ void k_prep(const float* __restrict__ q, const float* __restrict__ wq,
                       const float* __restrict__ bq, float* __restrict__ fq,
                       const float* __restrict__ wv, u16* __restrict__ wvtp) {
  __shared__ u16 tile[64][72];
  int tid = threadIdx.x;
  if (blockIdx.x < 256) {
    int blk = blockIdx.x;               // b(8) x jc(4) x dc(8)
    int b = blk >> 5, jc = (blk >> 3) & 3, dc = blk & 7;
    int j = jc * 256 + tid;
    const float* qb = q + b * Dn;
    float acc = 0.f;
    int d0 = dc * 128;
    for (int d = d0; d < d0 + 128; ++d)
      acc = fmaf(qb[d], wq[(size_t)d * Kn + j], acc);
    if (dc == 0) acc += bq[j];
    atomicAdd(&fq[b * Kn + j], acc);
  } else {
    int idx = blockIdx.x - 256;
    int k0 = (idx & 15) * 64, n0 = (idx >> 4) * 64;
    int r = tid >> 2, c0 = (tid & 3) * 16;
#pragma unroll
    for (int i = 0; i < 4; ++i) {
      float4 vv = *reinterpret_cast<const float4*>(wv + (size_t)(k0 + r) * Kn + n0 + c0 + i * 4);
      tile[r][c0 + i * 4 + 0] = f2bf(vv.x);
      tile[r][c0 + i * 4 + 1] = f2bf(vv.y);
      tile[r][c0 + i * 4 + 2] = f2bf(vv.z);
      tile[r][c0 + i * 4 + 3] = f2bf(vv.w);
    }
    __syncthreads();
    int n_l = tid >> 2, kcl = (tid & 3) * 16;
    int n_g = n0 + n_l;
    alignas(16) u16 o[16];
#pragma unroll
    for (int i = 0; i < 16; ++i) o[i] = tile[kcl + i][n_l];
    int b0 = k0 + kcl;        // 16-aligned
    int b1 = b0 + 8;
    size_t off0 = ((size_t)(n_g >> 4) * 32 + (b0 >> 5)) * 512 +
                  (size_t)((((b0 >> 3) & 3) * 16) + (n_g & 15)) * 8;
    size_t off1 = ((size_t)(n_g >> 4) * 32 + (b1 >> 5)) * 512 +
                  (size_t)((((b1 >> 3) & 3) * 16) + (n_g & 15)) * 8;
    *reinterpret_cast<u16x8*>(wvtp + off0) = *reinterpret_cast<u16x8*>(&o[0]);
    *reinterpret_cast<u16x8*>(wvtp + off1) = *reinterpret_cast<u16x8*>(&o[8]);
  }
}

// ---------------- k_gcb: g (blocks 0-2047) + cb (blocks 2048-2055) ----------------
__global__ void k_gcb(const float* __restrict__ wk, const float* __restrict__ fq,
                      const float* __restrict__ bk, float* __restrict__ g,
                      float* __restrict__ cb) {
  int tid = threadIdx.x;
  if (blockIdx.x < 2048) {
    int wid = (blockIdx.x * 256 + tid) >> 6;   // 8192 waves
    int lane = tid & 63;
    int b = wid >> 10, d = wid & 1023;
    const float* row = wk + (size_t)d * Kn;
    const float* f = fq + b * Kn;
    float acc = 0.f;
    for (int j = lane; j < Kn; j += 64) acc = fmaf(row[j], f[j], acc);
    for (int m = 32; m; m >>= 1) acc += __shfl_xor(acc, m, 64);
    if (lane == 0) g[b * Dn + d] = acc;
  } else if (tid < 64) {
    int b = blockIdx.x - 2048;
    float acc = 0.f;
    for (int j = tid; j < Kn; j += 64) acc = fmaf(fq[b * Kn + j], bk[j], acc);
    for (int m = 32; m; m >>= 1) acc += __shfl_xor(acc, m, 64);
    if (tid == 0) cb[b] = acc;
  }
}

// ---------------- attn = sigmoid((g.k_s + cb)/32), dual store ----------------
__global__ void k_attn(const float* __restrict__ kmat, const float* __restrict__ g,
                       const float* __restrict__ cb, float* __restrict__ out_attn,
                       float* __restrict__ attn_ws) {
  int row = blockIdx.x * 4 + (threadIdx.x >> 6);  // 32768
  int lane = threadIdx.x & 63;
  int b = row >> 12;
  const float4* kr = reinterpret_cast<const float4*>(kmat + (size_t)row * Dn);
  const float4* gr = reinterpret_cast<const float4*>(g + b * Dn);
  float acc = 0.f;
#pragma unroll
  for (int i = 0; i < 4; ++i) {
    float4 kv = kr[lane + 64 * i];
    float4 gv = gr[lane + 64 * i];
    acc = fmaf(kv.x, gv.x, acc); acc = fmaf(kv.y, gv.y, acc);
    acc = fmaf(kv.z, gv.z, acc); acc = fmaf(kv.w, gv.w, acc);
  }
  for (int m = 32; m; m >>= 1) acc += __shfl_xor(acc, m, 64);
  if (lane == 0) {
    float logit = (acc + cb[b]) * 0.03125f;
    float s = 1.f / (1.f + expf(-logit));
    out_attn[row] = s;
    attn_ws[row] = s;
  }
}

// ---------------- k_fv: fused fv GEMM + norm/clip + weighted seed reduce ---------
// 1024 threads = 16 waves; wave w owns cols [w*64,(w+1)*64) (4 col-tiles of 16).
// Block covers 64 rows (one b) x full N=1024. acc[4][4] = 64 regs/lane.
// A-tile: As[64][128] bf16 (16KB), XOR-swizzled; each thread stages one 16B chunk,
// fp32 source reg-prefetched one K-step ahead. B from wvtp (packed, L2-resident):
// per (ct,j,k0) one coalesced 1KB wave-load at uniform_base + lane*16B.
__global__ __launch_bounds__(1024)
void k_fv(const float* __restrict__ v, const u16* __restrict__ wvtp,
          const float* __restrict__ bv, const float* __restrict__ attn,
          float* __restrict__ seed_acc) {
  __shared__ u16 As[64 * 128];     // 16 KiB
  __shared__ float nrm[64];
  __shared__ float coef[64];

  int r0 = blockIdx.x * 64;
  int b  = r0 >> 12;
  int s0 = r0 & (Sn - 1);

  int tid = threadIdx.x;
  int wave = tid >> 6, lane = tid & 63;
  int m = lane & 15, qq = lane >> 4;

  if (tid < 64) nrm[tid] = 0.f;

  f32x4 acc[4][4];
#pragma unroll
  for (int i = 0; i < 4; ++i)
#pragma unroll
    for (int j = 0; j < 4; ++j) acc[i][j] = (f32x4){0.f, 0.f, 0.f, 0.f};

  // A staging: thread -> row tid>>4 (0..63), chunk tid&15 (0..15)
  int arow = tid >> 4, achunk = tid & 15;
  const float* gA0 = v + ((size_t)(b * Sn + s0) + arow) * Dn + achunk * 8;
  int apos = (achunk ^ (arow & 15)) * 8;   // u16 offset within row (swizzled)

  // B base per (wave,lane): packed fragments; per (ct,j,k0) add ((ct*32)+(k0>>5)+j)*512
  const u16* gBp = wvtp + (size_t)wave * 4 * 32 * 512 + (size_t)lane * 8;

  // prefetch first A chunk (8 floats)
  float4 pa0 = reinterpret_cast<const float4*>(gA0)[0];
  float4 pa1 = reinterpret_cast<const float4*>(gA0)[1];

  for (int k0 = 0; k0 < 1024; k0 += 128) {
    __syncthreads();
    {
      u16x8 o = { f2bf(pa0.x), f2bf(pa0.y), f2bf(pa0.z), f2bf(pa0.w),
                  f2bf(pa1.x), f2bf(pa1.y), f2bf(pa1.z), f2bf(pa1.w) };
      *reinterpret_cast<u16x8*>(&As[arow * 128 + apos]) = o;
    }
    if (k0 < 896) {   // issue next A load; overlaps with MFMA below
      const float4* pa = reinterpret_cast<const float4*>(gA0 + k0 + 128);
      pa0 = pa[0]; pa1 = pa[1];
    }
    __syncthreads();

#pragma unroll
    for (int j = 0; j < 4; ++j) {
      int c = j * 4 + qq;               // chunk 0..15 (K-slice c*8)
      bf16x8 a[4];
#pragma unroll
      for (int rt = 0; rt < 4; ++rt) {
        int r = rt * 16 + m;
        u16x8 raw = *reinterpret_cast<const u16x8*>(&As[r * 128 + ((c ^ (r & 15)) * 8)]);
        a[rt] = __builtin_bit_cast(bf16x8, raw);
      }
#pragma unroll
      for (int ct = 0; ct < 4; ++ct) {
        u16x8 raw = *reinterpret_cast<const u16x8*>(
            gBp + ((size_t)ct * 32 + (k0 >> 5) + j) * 512);
        bf16x8 bb = __builtin_bit_cast(bf16x8, raw);
#pragma unroll
        for (int rt = 0; rt < 4; ++rt)
          acc[rt][ct] = __builtin_amdgcn_mfma_f32_16x16x32_bf16(a[rt], bb, acc[rt][ct], 0, 0, 0);
      }
    }
  }

  // bias per owned col (C/D layout: col = lane&15, row = qq*4+reg)
  float bvv[4];
#pragma unroll
  for (int ct = 0; ct < 4; ++ct) bvv[ct] = bv[wave * 64 + ct * 16 + m];

  // row sum-of-squares: per (rt,reg) sum this lane's 4 cols, reduce over m
#pragma unroll
  for (int rt = 0; rt < 4; ++rt) {
#pragma unroll
    for (int reg = 0; reg < 4; ++reg) {
      float ss = 0.f;
#pragma unroll
      for (int ct = 0; ct < 4; ++ct) {
        float f = acc[rt][ct][reg] + bvv[ct];
        ss = fmaf(f, f, ss);
      }
      ss += __shfl_xor(ss, 1, 64);
      ss += __shfl_xor(ss, 2, 64);
      ss += __shfl_xor(ss, 4, 64);
      ss += __shfl_xor(ss, 8, 64);
      if (m == 0) atomicAdd(&nrm[rt * 16 + qq * 4 + reg], ss);
    }
  }
  __syncthreads();
  if (tid < 64)
    coef[tid] = attn[b * Sn + s0 + tid] / fmaxf(1.f, sqrtf(nrm[tid]));
  __syncthreads();

  // weighted reduce over rows: seed[b, col] += sum_rows coef[row]*(fv+bv)
#pragma unroll
  for (int ct = 0; ct < 4; ++ct) {
    float t = 0.f;
#pragma unroll
    for (int rt = 0; rt < 4; ++rt) {
#pragma unroll
      for (int reg = 0; reg < 4; ++reg) {
        float cf = coef[rt * 16 + qq * 4 + reg];
        t = fmaf(cf, acc[rt][ct][reg] + bvv[ct], t);
      }
    }
    t += __shfl_xor(t, 16, 64);
    t += __shfl_xor(t, 32, 64);
    if (qq == 0) atomicAdd(&seed_acc[b * Kn + wave * 64 + ct * 16 + m], t);
  }
}

// ---------------- k_final: out = seed_acc + 0.1*noise ----------------
__global__ void k_final(const float* __restrict__ seed_acc, float* __restrict__ out) {
  int t = blockIdx.x * 256 + threadIdx.x;   // 8192
  uint32_t o0, o1;
  threefry2x32(0u, 1234u, 0u, (uint32_t)t, &o0, &o1);
  uint32_t bits = o0 ^ o1;
  float f = __uint_as_float((bits >> 9) | 0x3F800000u) - 1.0f;
  float lo = __uint_as_float(0xBF7FFFFFu);
  float u = f * (1.0f - lo) + lo;
  u = fmaxf(u, lo);
  out[t] = seed_acc[t] + 1.41421356237f * erfinv_f(u) * 0.1f;
}

extern "C" void kernel_launch(void* const* d_in, const int* in_sizes, int n_in,
                              void* d_out, int out_size, void* d_ws, size_t ws_size,
                              hipStream_t stream) {
  const float* q  = (const float*)d_in[0];
  const float* k  = (const float*)d_in[1];
  const float* v  = (const float*)d_in[2];
  const float* wq = (const float*)d_in[3];
  const float* bq = (const float*)d_in[4];
  const float* wk = (const float*)d_in[5];
  const float* bk = (const float*)d_in[6];
  const float* wv = (const float*)d_in[7];
  const float* bv = (const float*)d_in[8];
  float* out = (float*)d_out;
  float* ws = (float*)d_ws;

  // ws floats: fq[0,8192) seed_acc[8192,16384) g[16384,24576) cb[24576,24584)
  //            attn_ws[24832,57600) ; wvtp bytes @ [262144, 262144+2MiB)
  float* fq       = ws;
  float* seed_acc = ws + 8192;
  float* g        = ws + 16384;
  float* cb       = ws + 24576;
  float* attn_ws  = ws + 24832;
  u16* wvtp = (u16*)((char*)d_ws + 262144);

  hipMemsetAsync(ws, 0, 16384 * sizeof(float), stream);       // fq + seed_acc
  k_prep <<<512,  256, 0, stream>>>(q, wq, bq, fq, wv, wvtp);
  k_gcb  <<<2056, 256, 0, stream>>>(wk, fq, bk, g, cb);
  k_attn <<<8192, 256, 0, stream>>>(k, g, cb, out + 8192, attn_ws);
  k_fv   <<<512, 1024, 0, stream>>>(v, wvtp, bv, attn_ws, seed_acc);
  k_final<<<32,   256, 0, stream>>>(seed_acc, out);
}

// Round 7
// 390.971 us; speedup vs baseline: 1.1381x; 1.0129x over previous
//
#include <hip/hip_runtime.h>
#include <stdint.h>

// DP_Attention: B=8, S=4096, D=K=1024, fp32.
// Fused structure (6 dispatches):
//   memset(fq, seed_acc)
//   k_prep : blocks 0-255 fq = q@Wq+bq (split-K atomic); 256-511 wvtp = bf16 Wv
//            packed in MFMA-fragment order (per 16-col tile x 32-k slice: 64
//            lanes' 16B fragments contiguous -> k_fv B loads are lane*16B coalesced)
//   k_gcb  : blocks 0-2047 g[b]=Wk@fq[b]; 2048-2055 cb[b]=fq[b].bk
//   k_attn : attn = sigmoid((g.k_s+cb)/32)  -> d_out[8192:] and attn_ws
//   k_fv   : 1024-thr block: 64 fv rows x FULL N=1024, 16 waves (64 cols each),
//            acc[4][4]=64 regs/lane. BK=128 A-tile (16KB swizzled LDS,
//            reg-prefetched with NON-TEMPORAL v loads). B from wvtp: 1KB
//            coalesced loads, L2-resident. Row norm in-block -> coef ->
//            atomicAdd sum_s coef*(fv+bv) into seed_acc.
//   k_final: out = seed_acc + 0.1*noise (threefry, partitioned)
// R5 post-mortem: B service rate ~10-13 B/cyc/CU invariant to occupancy (r3 vs r4)
// and access pattern (r4 vs r5) -> L3 bandwidth wall. v streaming evicts the 2MiB
// wvtp from each XCD L2 -> every block refetches B from L3 (1 GB total). This
// round: v loads are non-temporal so wvtp stays L2-resident.
// R6 fix: __builtin_nontemporal_load requires a clang ext_vector pointer, not
// HIP's float4 struct -> load via f32x4v (ext_vector_type(4) float).

#define Bn 8
#define Sn 4096
#define Dn 1024
#define Kn 1024

typedef unsigned short u16;
typedef __attribute__((ext_vector_type(8))) unsigned short u16x8;
typedef __attribute__((ext_vector_type(8))) __bf16 bf16x8;
typedef __attribute__((ext_vector_type(4))) float f32x4;
typedef __attribute__((ext_vector_type(4))) float f32x4v;

__device__ __forceinline__ u16 f2bf(float f) {
  uint32_t x = __float_as_uint(f);
  x += 0x7FFFu + ((x >> 16) & 1u);   // RNE
  return (u16)(x >> 16);
}

// ---------------- JAX threefry2x32 (key=(0,1234)), partitionable ----------------
__device__ __forceinline__ uint32_t rotl32(uint32_t x, int d) {
  return (x << d) | (x >> (32 - d));
}
__device__ void threefry2x32(uint32_t k0, uint32_t k1, uint32_t x0, uint32_t x1,
                             uint32_t* o0, uint32_t* o1) {
  uint32_t ks0 = k0, ks1 = k1, ks2 = k0 ^ k1 ^ 0x1BD11BDAu;
  x0 += ks0; x1 += ks1;
#define TF_R4(a,b,c,d) \
  x0 += x1; x1 = rotl32(x1,a); x1 ^= x0; \
  x0 += x1; x1 = rotl32(x1,b); x1 ^= x0; \
  x0 += x1; x1 = rotl32(x1,c); x1 ^= x0; \
  x0 += x1; x1 = rotl32(x1,d); x1 ^= x0;
  TF_R4(13,15,26,6);  x0 += ks1; x1 += ks2 + 1u;
  TF_R4(17,29,16,24); x0 += ks2; x1 += ks0 + 2u;
  TF_R4(13,15,26,6);  x0 += ks0; x1 += ks1 + 3u;
  TF_R4(17,29,16,24); x0 += ks1; x1 += ks2 + 4u;
  TF_R4(13,15,26,6);  x0 += ks2; x1 += ks0 + 5u;
#undef TF_R4
  *o0 = x0; *o1 = x1;
}

__device__ float erfinv_f(float x) {
  float w = -log1pf(-x * x);
  float p;
  if (w < 5.0f) {
    w -= 2.5f;
    p = 2.81022636e-08f;
    p = fmaf(p, w, 3.43273939e-07f);
    p = fmaf(p, w, -3.5233877e-06f);
    p = fmaf(p, w, -4.39150654e-06f);
    p = fmaf(p, w, 0.00021858087f);
    p = fmaf(p, w, -0.00125372503f);
    p = fmaf(p, w, -0.00417768164f);
    p = fmaf(p, w, 0.246640727f);
    p = fmaf(p, w, 1.50140941f);
  } else {
    w = sqrtf(w) - 3.0f;
    p = -0.000200214257f;
    p = fmaf(p, w, 0.000100950558f);
    p = fmaf(p, w, 0.00134934322f);
    p = fmaf(p, w, -0.00367342844f);
    p = fmaf(p, w, 0.00573950773f);
    p = fmaf(p, w, -0.0076224613f);
    p = fmaf(p, w, 0.00943887047f);
    p = fmaf(p, w, 1.00167406f);
    p = fmaf(p, w, 2.83297682f);
  }
  return p * x;
}

// ---------------- k_prep: fq (blocks 0-255) + Wv pack (blocks 256-511) ----------
// Packed layout (u16 units): for global col n, k:
//   off = ((n>>4)*32 + (k>>5))*512 + (((k>>3)&3)*16 + (n&15))*8 + (k&7)
__global__ void k_prep(const float* __restrict__ q, const float* __restrict__ wq,
                       const float* __restrict__ bq, float* __restrict__ fq,
                       const float* __restrict__ wv, u16* __restrict__ wvtp) {
  __shared__ u16 tile[64][72];
  int tid = threadIdx.x;
  if (blockIdx.x < 256) {
    int blk = blockIdx.x;               // b(8) x jc(4) x dc(8)
    int b = blk >> 5, jc = (blk >> 3) & 3, dc = blk & 7;
    int j = jc * 256 + tid;
    const float* qb = q + b * Dn;
    float acc = 0.f;
    int d0 = dc * 128;
    for (int d = d0; d < d0 + 128; ++d)
      acc = fmaf(qb[d], wq[(size_t)d * Kn + j], acc);
    if (dc == 0) acc += bq[j];
    atomicAdd(&fq[b * Kn + j], acc);
  } else {
    int idx = blockIdx.x - 256;
    int k0 = (idx & 15) * 64, n0 = (idx >> 4) * 64;
    int r = tid >> 2, c0 = (tid & 3) * 16;
#pragma unroll
    for (int i = 0; i < 4; ++i) {
      float4 vv = *reinterpret_cast<const float4*>(wv + (size_t)(k0 + r) * Kn + n0 + c0 + i * 4);
      tile[r][c0 + i * 4 + 0] = f2bf(vv.x);
      tile[r][c0 + i * 4 + 1] = f2bf(vv.y);
      tile[r][c0 + i * 4 + 2] = f2bf(vv.z);
      tile[r][c0 + i * 4 + 3] = f2bf(vv.w);
    }
    __syncthreads();
    int n_l = tid >> 2, kcl = (tid & 3) * 16;
    int n_g = n0 + n_l;
    alignas(16) u16 o[16];
#pragma unroll
    for (int i = 0; i < 16; ++i) o[i] = tile[kcl + i][n_l];
    int b0 = k0 + kcl;        // 16-aligned
    int b1 = b0 + 8;
    size_t off0 = ((size_t)(n_g >> 4) * 32 + (b0 >> 5)) * 512 +
                  (size_t)((((b0 >> 3) & 3) * 16) + (n_g & 15)) * 8;
    size_t off1 = ((size_t)(n_g >> 4) * 32 + (b1 >> 5)) * 512 +
                  (size_t)((((b1 >> 3) & 3) * 16) + (n_g & 15)) * 8;
    *reinterpret_cast<u16x8*>(wvtp + off0) = *reinterpret_cast<u16x8*>(&o[0]);
    *reinterpret_cast<u16x8*>(wvtp + off1) = *reinterpret_cast<u16x8*>(&o[8]);
  }
}

// ---------------- k_gcb: g (blocks 0-2047) + cb (blocks 2048-2055) ----------------
__global__ void k_gcb(const float* __restrict__ wk, const float* __restrict__ fq,
                      const float* __restrict__ bk, float* __restrict__ g,
                      float* __restrict__ cb) {
  int tid = threadIdx.x;
  if (blockIdx.x < 2048) {
    int wid = (blockIdx.x * 256 + tid) >> 6;   // 8192 waves
    int lane = tid & 63;
    int b = wid >> 10, d = wid & 1023;
    const float* row = wk + (size_t)d * Kn;
    const float* f = fq + b * Kn;
    float acc = 0.f;
    for (int j = lane; j < Kn; j += 64) acc = fmaf(row[j], f[j], acc);
    for (int m = 32; m; m >>= 1) acc += __shfl_xor(acc, m, 64);
    if (lane == 0) g[b * Dn + d] = acc;
  } else if (tid < 64) {
    int b = blockIdx.x - 2048;
    float acc = 0.f;
    for (int j = tid; j < Kn; j += 64) acc = fmaf(fq[b * Kn + j], bk[j], acc);
    for (int m = 32; m; m >>= 1) acc += __shfl_xor(acc, m, 64);
    if (tid == 0) cb[b] = acc;
  }
}

// ---------------- attn = sigmoid((g.k_s + cb)/32), dual store ----------------
__global__ void k_attn(const float* __restrict__ kmat, const float* __restrict__ g,
                       const float* __restrict__ cb, float* __restrict__ out_attn,
                       float* __restrict__ attn_ws) {
  int row = blockIdx.x * 4 + (threadIdx.x >> 6);  // 32768
  int lane = threadIdx.x & 63;
  int b = row >> 12;
  const float4* kr = reinterpret_cast<const float4*>(kmat + (size_t)row * Dn);
  const float4* gr = reinterpret_cast<const float4*>(g + b * Dn);
  float acc = 0.f;
#pragma unroll
  for (int i = 0; i < 4; ++i) {
    float4 kv = kr[lane + 64 * i];
    float4 gv = gr[lane + 64 * i];
    acc = fmaf(kv.x, gv.x, acc); acc = fmaf(kv.y, gv.y, acc);
    acc = fmaf(kv.z, gv.z, acc); acc = fmaf(kv.w, gv.w, acc);
  }
  for (int m = 32; m; m >>= 1) acc += __shfl_xor(acc, m, 64);
  if (lane == 0) {
    float logit = (acc + cb[b]) * 0.03125f;
    float s = 1.f / (1.f + expf(-logit));
    out_attn[row] = s;
    attn_ws[row] = s;
  }
}

// ---------------- k_fv: fused fv GEMM + norm/clip + weighted seed reduce ---------
// 1024 threads = 16 waves; wave w owns cols [w*64,(w+1)*64) (4 col-tiles of 16).
// Block covers 64 rows (one b) x full N=1024. acc[4][4] = 64 regs/lane.
// A-tile: As[64][128] bf16 (16KB), XOR-swizzled; each thread stages one 16B chunk,
// fp32 source reg-prefetched one K-step ahead with NON-TEMPORAL loads (v is
// stream-once; keeps wvtp L2-resident). B from wvtp (packed): per (ct,j,k0) one
// coalesced 1KB wave-load at uniform_base + lane*16B.
__global__ __launch_bounds__(1024)
void k_fv(const float* __restrict__ v, const u16* __restrict__ wvtp,
          const float* __restrict__ bv, const float* __restrict__ attn,
          float* __restrict__ seed_acc) {
  __shared__ u16 As[64 * 128];     // 16 KiB
  __shared__ float nrm[64];
  __shared__ float coef[64];

  int r0 = blockIdx.x * 64;
  int b  = r0 >> 12;
  int s0 = r0 & (Sn - 1);

  int tid = threadIdx.x;
  int wave = tid >> 6, lane = tid & 63;
  int m = lane & 15, qq = lane >> 4;

  if (tid < 64) nrm[tid] = 0.f;

  f32x4 acc[4][4];
#pragma unroll
  for (int i = 0; i < 4; ++i)
#pragma unroll
    for (int j = 0; j < 4; ++j) acc[i][j] = (f32x4){0.f, 0.f, 0.f, 0.f};

  // A staging: thread -> row tid>>4 (0..63), chunk tid&15 (0..15)
  int arow = tid >> 4, achunk = tid & 15;
  const float* gA0 = v + ((size_t)(b * Sn + s0) + arow) * Dn + achunk * 8;
  int apos = (achunk ^ (arow & 15)) * 8;   // u16 offset within row (swizzled)

  // B base per (wave,lane): packed fragments; per (ct,j,k0) add ((ct*32)+(k0>>5)+j)*512
  const u16* gBp = wvtp + (size_t)wave * 4 * 32 * 512 + (size_t)lane * 8;

  // prefetch first A chunk (8 floats) — non-temporal (v is stream-once)
  f32x4v pa0 = __builtin_nontemporal_load(reinterpret_cast<const f32x4v*>(gA0));
  f32x4v pa1 = __builtin_nontemporal_load(reinterpret_cast<const f32x4v*>(gA0) + 1);

  for (int k0 = 0; k0 < 1024; k0 += 128) {
    __syncthreads();
    {
      u16x8 o = { f2bf(pa0[0]), f2bf(pa0[1]), f2bf(pa0[2]), f2bf(pa0[3]),
                  f2bf(pa1[0]), f2bf(pa1[1]), f2bf(pa1[2]), f2bf(pa1[3]) };
      *reinterpret_cast<u16x8*>(&As[arow * 128 + apos]) = o;
    }
    if (k0 < 896) {   // issue next A load; overlaps with MFMA below
      const f32x4v* pa = reinterpret_cast<const f32x4v*>(gA0 + k0 + 128);
      pa0 = __builtin_nontemporal_load(pa);
      pa1 = __builtin_nontemporal_load(pa + 1);
    }
    __syncthreads();

#pragma unroll
    for (int j = 0; j < 4; ++j) {
      int c = j * 4 + qq;               // chunk 0..15 (K-slice c*8)
      bf16x8 a[4];
#pragma unroll
      for (int rt = 0; rt < 4; ++rt) {
        int r = rt * 16 + m;
        u16x8 raw = *reinterpret_cast<const u16x8*>(&As[r * 128 + ((c ^ (r & 15)) * 8)]);
        a[rt] = __builtin_bit_cast(bf16x8, raw);
      }
#pragma unroll
      for (int ct = 0; ct < 4; ++ct) {
        u16x8 raw = *reinterpret_cast<const u16x8*>(
            gBp + ((size_t)ct * 32 + (k0 >> 5) + j) * 512);
        bf16x8 bb = __builtin_bit_cast(bf16x8, raw);
#pragma unroll
        for (int rt = 0; rt < 4; ++rt)
          acc[rt][ct] = __builtin_amdgcn_mfma_f32_16x16x32_bf16(a[rt], bb, acc[rt][ct], 0, 0, 0);
      }
    }
  }

  // bias per owned col (C/D layout: col = lane&15, row = qq*4+reg)
  float bvv[4];
#pragma unroll
  for (int ct = 0; ct < 4; ++ct) bvv[ct] = bv[wave * 64 + ct * 16 + m];

  // row sum-of-squares: per (rt,reg) sum this lane's 4 cols, reduce over m
#pragma unroll
  for (int rt = 0; rt < 4; ++rt) {
#pragma unroll
    for (int reg = 0; reg < 4; ++reg) {
      float ss = 0.f;
#pragma unroll
      for (int ct = 0; ct < 4; ++ct) {
        float f = acc[rt][ct][reg] + bvv[ct];
        ss = fmaf(f, f, ss);
      }
      ss += __shfl_xor(ss, 1, 64);
      ss += __shfl_xor(ss, 2, 64);
      ss += __shfl_xor(ss, 4, 64);
      ss += __shfl_xor(ss, 8, 64);
      if (m == 0) atomicAdd(&nrm[rt * 16 + qq * 4 + reg], ss);
    }
  }
  __syncthreads();
  if (tid < 64)
    coef[tid] = attn[b * Sn + s0 + tid] / fmaxf(1.f, sqrtf(nrm[tid]));
  __syncthreads();

  // weighted reduce over rows: seed[b, col] += sum_rows coef[row]*(fv+bv)
#pragma unroll
  for (int ct = 0; ct < 4; ++ct) {
    float t = 0.f;
#pragma unroll
    for (int rt = 0; rt < 4; ++rt) {
#pragma unroll
      for (int reg = 0; reg < 4; ++reg) {
        float cf = coef[rt * 16 + qq * 4 + reg];
        t = fmaf(cf, acc[rt][ct][reg] + bvv[ct], t);
      }
    }
    t += __shfl_xor(t, 16, 64);
    t += __shfl_xor(t, 32, 64);
    if (qq == 0) atomicAdd(&seed_acc[b * Kn + wave * 64 + ct * 16 + m], t);
  }
}

// ---------------- k_final: out = seed_acc + 0.1*noise ----------------
__global__ void k_final(const float* __restrict__ seed_acc, float* __restrict__ out) {
  int t = blockIdx.x * 256 + threadIdx.x;   // 8192
  uint32_t o0, o1;
  threefry2x32(0u, 1234u, 0u, (uint32_t)t, &o0, &o1);
  uint32_t bits = o0 ^ o1;
  float f = __uint_as_float((bits >> 9) | 0x3F800000u) - 1.0f;
  float lo = __uint_as_float(0xBF7FFFFFu);
  float u = f * (1.0f - lo) + lo;
  u = fmaxf(u, lo);
  out[t] = seed_acc[t] + 1.41421356237f * erfinv_f(u) * 0.1f;
}

extern "C" void kernel_launch(void* const* d_in, const int* in_sizes, int n_in,
                              void* d_out, int out_size, void* d_ws, size_t ws_size,
                              hipStream_t stream) {
  const float* q  = (const float*)d_in[0];
  const float* k  = (const float*)d_in[1];
  const float* v  = (const float*)d_in[2];
  const float* wq = (const float*)d_in[3];
  const float* bq = (const float*)d_in[4];
  const float* wk = (const float*)d_in[5];
  const float* bk = (const float*)d_in[6];
  const float* wv = (const float*)d_in[7];
  const float* bv = (const float*)d_in[8];
  float* out = (float*)d_out;
  float* ws = (float*)d_ws;

  // ws floats: fq[0,8192) seed_acc[8192,16384) g[16384,24576) cb[24576,24584)
  //            attn_ws[24832,57600) ; wvtp bytes @ [262144, 262144+2MiB)
  float* fq       = ws;
  float* seed_acc = ws + 8192;
  float* g        = ws + 16384;
  float* cb       = ws + 24576;
  float* attn_ws  = ws + 24832;
  u16* wvtp = (u16*)((char*)d_ws + 262144);

  hipMemsetAsync(ws, 0, 16384 * sizeof(float), stream);       // fq + seed_acc
  k_prep <<<512,  256, 0, stream>>>(q, wq, bq, fq, wv, wvtp);
  k_gcb  <<<2056, 256, 0, stream>>>(wk, fq, bk, g, cb);
  k_attn <<<8192, 256, 0, stream>>>(k, g, cb, out + 8192, attn_ws);
  k_fv   <<<512, 1024, 0, stream>>>(v, wvtp, bv, attn_ws, seed_acc);
  k_final<<<32,   256, 0, stream>>>(seed_acc, out);
}